// Round 1
// baseline (553.920 us; speedup 1.0000x reference)
//
#include <hip/hip_runtime.h>
#include <math.h>

#define NN 10000
#define DD 256
#define QQ 4096
#define CAP 128   // max neighbors kept per row; Binom(10000,0.003) tail @128 ~ 0

// ws layout:
//   float xn[NN*DD]      normalized x rows
//   int   cnt[NN]        neighbor count per row (clamped to CAP)
//   int   nbr[NN*CAP]    neighbor indices per row

__global__ __launch_bounds__(256) void build_rows(
    const float* __restrict__ emb, const float* __restrict__ adj,
    float* __restrict__ xn, int* __restrict__ cnt, int* __restrict__ nbr)
{
    const int i = blockIdx.x;
    const int t = threadIdx.x;            // t in [0,256) == dim index
    __shared__ int   s_cnt;
    __shared__ int   s_list[CAP];
    __shared__ float s_red[4];
    __shared__ float s_norm;

    if (t == 0) s_cnt = 0;
    __syncthreads();

    // scan adjacency row i: 10000 floats = 2500 float4, coalesced
    const float4* row = (const float4*)(adj + (size_t)i * NN);
    for (int k = t; k < NN / 4; k += 256) {
        float4 v = row[k];
        int base = k * 4;
        if (v.x != 0.f) { int p = atomicAdd(&s_cnt, 1); if (p < CAP) s_list[p] = base;     }
        if (v.y != 0.f) { int p = atomicAdd(&s_cnt, 1); if (p < CAP) s_list[p] = base + 1; }
        if (v.z != 0.f) { int p = atomicAdd(&s_cnt, 1); if (p < CAP) s_list[p] = base + 2; }
        if (v.w != 0.f) { int p = atomicAdd(&s_cnt, 1); if (p < CAP) s_list[p] = base + 3; }
    }
    __syncthreads();

    const int c = s_cnt;
    const int m = (c < CAP) ? c : CAP;

    // aggregate neighbor embeddings: x = emb[i] + (sum_j emb[j]) / (deg + 1e-6)
    float acc = 0.f;
    for (int k = 0; k < m; ++k)
        acc += emb[(size_t)s_list[k] * DD + t];     // coalesced 1KB row reads (L2-hot)

    const float deg = (float)c + 1e-6f;
    const float x = emb[(size_t)i * DD + t] + acc / deg;

    // row norm: reduce x*x over 256 threads (4 waves of 64)
    float s = x * x;
    #pragma unroll
    for (int o = 32; o > 0; o >>= 1) s += __shfl_down(s, o, 64);
    const int lane = t & 63, wv = t >> 6;
    if (lane == 0) s_red[wv] = s;
    __syncthreads();
    if (t == 0) {
        float tot = s_red[0] + s_red[1] + s_red[2] + s_red[3];
        s_norm = fmaxf(sqrtf(tot), 1e-8f);
    }
    __syncthreads();

    xn[(size_t)i * DD + t] = x / s_norm;

    // persist CSR
    if (t == 0) cnt[i] = m;
    for (int k = t; k < m; k += 256) nbr[(size_t)i * CAP + k] = s_list[k];
}

__global__ __launch_bounds__(256) void edge_weights(
    const int* __restrict__ edges, const float* __restrict__ xn,
    const int* __restrict__ cnt, const int* __restrict__ nbr,
    float* __restrict__ out)
{
    const int e = blockIdx.x;
    const int t = threadIdx.x;            // dim index
    const int srcI = edges[e];
    const int dstI = edges[QQ + e];

    __shared__ int   s_dst[CAP];
    __shared__ int   s_com[CAP];
    __shared__ int   s_ncom;
    __shared__ float s_red[8];
    __shared__ float s_w;

    const int cs = cnt[srcI];
    const int cd = cnt[dstI];
    if (t == 0) { s_ncom = 0; s_w = 0.f; }
    for (int k = t; k < cd; k += 256) s_dst[k] = nbr[(size_t)dstI * CAP + k];
    __syncthreads();

    // intersect src neighbor list against dst list (each ~30 entries)
    for (int k = t; k < cs; k += 256) {
        int a = nbr[(size_t)srcI * CAP + k];
        bool found = false;
        for (int j = 0; j < cd; ++j) { if (s_dst[j] == a) { found = true; break; } }
        if (found) { int p = atomicAdd(&s_ncom, 1); s_com[p] = a; }
    }
    __syncthreads();

    const int nc = s_ncom;
    const float vs = xn[(size_t)srcI * DD + t];
    const float vd = xn[(size_t)dstI * DD + t];
    const int lane = t & 63, wv = t >> 6;

    for (int k = 0; k < nc; ++k) {
        const float vc = xn[(size_t)s_com[k] * DD + t];
        float a = vs * vc;
        float b = vd * vc;
        #pragma unroll
        for (int o = 32; o > 0; o >>= 1) {
            a += __shfl_down(a, o, 64);
            b += __shfl_down(b, o, 64);
        }
        if (lane == 0) { s_red[wv] = a; s_red[4 + wv] = b; }
        __syncthreads();
        if (t == 0) {
            float sa = s_red[0] + s_red[1] + s_red[2] + s_red[3];
            float sb = s_red[4] + s_red[5] + s_red[6] + s_red[7];
            s_w += sa * sb;
        }
        __syncthreads();
    }

    if (t == 0) out[e] = 1.f / (1.f + expf(-s_w));
}

extern "C" void kernel_launch(void* const* d_in, const int* in_sizes, int n_in,
                              void* d_out, int out_size, void* d_ws, size_t ws_size,
                              hipStream_t stream) {
    const float* emb   = (const float*)d_in[0];   // [N, D] fp32
    const float* adj   = (const float*)d_in[1];   // [N, N] fp32 (0/1)
    const int*   edges = (const int*)d_in[2];     // [2, Q] int32
    float*       out   = (float*)d_out;           // [Q] fp32

    float* xn  = (float*)d_ws;
    int*   cnt = (int*)(xn + (size_t)NN * DD);
    int*   nbr = cnt + NN;

    build_rows<<<NN, 256, 0, stream>>>(emb, adj, xn, cnt, nbr);
    edge_weights<<<QQ, 256, 0, stream>>>(edges, xn, cnt, nbr, out);
}

// Round 2
// 542.110 us; speedup vs baseline: 1.0218x; 1.0218x over previous
//
#include <hip/hip_runtime.h>
#include <math.h>

#define NN 10000
#define DD 256
#define QQ 4096
#define CAP 128   // max neighbors kept per row; Binom(10000,0.003) tail @128 ~ 0

// ws layout:
//   float xn[NN*DD]      normalized x rows
//   int   cnt[NN]        neighbor count per row (clamped to CAP)
//   int   nbr[NN*CAP]    neighbor indices per row

__global__ __launch_bounds__(256) void build_rows(
    const float* __restrict__ emb, const float* __restrict__ adj,
    float* __restrict__ xn, int* __restrict__ cnt, int* __restrict__ nbr)
{
    const int i = blockIdx.x;
    const int t = threadIdx.x;            // t in [0,256) == dim index
    __shared__ int   s_cnt;
    __shared__ int   s_list[CAP];
    __shared__ float s_red[4];
    __shared__ float s_norm;

    if (t == 0) s_cnt = 0;
    __syncthreads();

    // --- scan adjacency row i: preload ALL float4s into registers first so
    // the 10 loads are issued back-to-back (10 outstanding per thread),
    // then do the branchy nonzero scan on registers.
    const float4* row = (const float4*)(adj + (size_t)i * NN);
    float4 r[10];
    #pragma unroll
    for (int j = 0; j < 10; ++j) {
        int k = t + j * 256;
        r[j] = (k < NN / 4) ? row[k] : make_float4(0.f, 0.f, 0.f, 0.f);
    }
    #pragma unroll
    for (int j = 0; j < 10; ++j) {
        float4 v = r[j];
        int base = (t + j * 256) * 4;
        if (v.x != 0.f) { int p = atomicAdd(&s_cnt, 1); if (p < CAP) s_list[p] = base;     }
        if (v.y != 0.f) { int p = atomicAdd(&s_cnt, 1); if (p < CAP) s_list[p] = base + 1; }
        if (v.z != 0.f) { int p = atomicAdd(&s_cnt, 1); if (p < CAP) s_list[p] = base + 2; }
        if (v.w != 0.f) { int p = atomicAdd(&s_cnt, 1); if (p < CAP) s_list[p] = base + 3; }
    }
    __syncthreads();

    const int c = s_cnt;
    const int m = (c < CAP) ? c : CAP;

    // --- aggregate neighbor embeddings with 8 independent accumulators so 8
    // loads are in flight per thread (breaks the 1-outstanding-load chain).
    float a0=0.f,a1=0.f,a2=0.f,a3=0.f,a4=0.f,a5=0.f,a6=0.f,a7=0.f;
    int k = 0;
    for (; k + 8 <= m; k += 8) {
        int i0=s_list[k],   i1=s_list[k+1], i2=s_list[k+2], i3=s_list[k+3];
        int i4=s_list[k+4], i5=s_list[k+5], i6=s_list[k+6], i7=s_list[k+7];
        a0 += emb[(size_t)i0*DD + t]; a1 += emb[(size_t)i1*DD + t];
        a2 += emb[(size_t)i2*DD + t]; a3 += emb[(size_t)i3*DD + t];
        a4 += emb[(size_t)i4*DD + t]; a5 += emb[(size_t)i5*DD + t];
        a6 += emb[(size_t)i6*DD + t]; a7 += emb[(size_t)i7*DD + t];
    }
    for (; k < m; ++k) a0 += emb[(size_t)s_list[k]*DD + t];
    const float acc = ((a0+a1)+(a2+a3)) + ((a4+a5)+(a6+a7));

    const float deg = (float)c + 1e-6f;
    const float x = emb[(size_t)i * DD + t] + acc / deg;

    // row norm: reduce x*x over 256 threads (4 waves of 64)
    float s = x * x;
    #pragma unroll
    for (int o = 32; o > 0; o >>= 1) s += __shfl_down(s, o, 64);
    const int lane = t & 63, wv = t >> 6;
    if (lane == 0) s_red[wv] = s;
    __syncthreads();
    if (t == 0) {
        float tot = s_red[0] + s_red[1] + s_red[2] + s_red[3];
        s_norm = fmaxf(sqrtf(tot), 1e-8f);
    }
    __syncthreads();

    xn[(size_t)i * DD + t] = x / s_norm;

    if (t == 0) cnt[i] = m;
    for (int q = t; q < m; q += 256) nbr[(size_t)i * CAP + q] = s_list[q];
}

// One wave (64 threads) per edge. Intersect first; ~91% of edges have zero
// common neighbors -> early-exit with sigmoid(0)=0.5 and never touch xn.
__global__ __launch_bounds__(64) void edge_weights(
    const int* __restrict__ edges, const float* __restrict__ xn,
    const int* __restrict__ cnt, const int* __restrict__ nbr,
    float* __restrict__ out)
{
    const int e = blockIdx.x;
    const int lane = threadIdx.x;
    const int srcI = edges[e];
    const int dstI = edges[QQ + e];

    __shared__ int s_dst[CAP];
    __shared__ int s_com[CAP];
    __shared__ int s_ncom;

    const int cs = cnt[srcI];
    const int cd = cnt[dstI];
    if (lane == 0) s_ncom = 0;
    for (int q = lane; q < cd; q += 64) s_dst[q] = nbr[(size_t)dstI * CAP + q];
    __syncthreads();   // single wave: compiles to waitcnt, cheap

    for (int q = lane; q < cs; q += 64) {
        int a = nbr[(size_t)srcI * CAP + q];
        bool found = false;
        for (int j = 0; j < cd; ++j) { if (s_dst[j] == a) { found = true; break; } }
        if (found) { int p = atomicAdd(&s_ncom, 1); s_com[p] = a; }
    }
    __syncthreads();

    const int nc = s_ncom;
    if (nc == 0) { if (lane == 0) out[e] = 0.5f; return; }

    const float4 vs = ((const float4*)(xn + (size_t)srcI * DD))[lane];
    const float4 vd = ((const float4*)(xn + (size_t)dstI * DD))[lane];

    float w = 0.f;
    for (int q = 0; q < nc; ++q) {
        const float4 vc = ((const float4*)(xn + (size_t)s_com[q] * DD))[lane];
        float a = vs.x*vc.x + vs.y*vc.y + vs.z*vc.z + vs.w*vc.w;
        float b = vd.x*vc.x + vd.y*vc.y + vd.z*vc.z + vd.w*vc.w;
        #pragma unroll
        for (int o = 32; o > 0; o >>= 1) {
            a += __shfl_xor(a, o, 64);
            b += __shfl_xor(b, o, 64);
        }
        w += a * b;
    }
    if (lane == 0) out[e] = 1.f / (1.f + expf(-w));
}

extern "C" void kernel_launch(void* const* d_in, const int* in_sizes, int n_in,
                              void* d_out, int out_size, void* d_ws, size_t ws_size,
                              hipStream_t stream) {
    const float* emb   = (const float*)d_in[0];   // [N, D] fp32
    const float* adj   = (const float*)d_in[1];   // [N, N] fp32 (0/1)
    const int*   edges = (const int*)d_in[2];     // [2, Q] int32
    float*       out   = (float*)d_out;           // [Q] fp32

    float* xn  = (float*)d_ws;
    int*   cnt = (int*)(xn + (size_t)NN * DD);
    int*   nbr = cnt + NN;

    build_rows<<<NN, 256, 0, stream>>>(emb, adj, xn, cnt, nbr);
    edge_weights<<<QQ, 64, 0, stream>>>(edges, xn, cnt, nbr, out);
}

// Round 4
// 534.674 us; speedup vs baseline: 1.0360x; 1.0139x over previous
//
#include <hip/hip_runtime.h>
#include <math.h>

#define NN 10000
#define DD 256
#define QQ 4096
#define CAP 128   // max neighbors kept per row; Binom(10000,0.003) tail @128 ~ 0

typedef float  fx4 __attribute__((ext_vector_type(4)));   // native vec for nontemporal builtin

// ws layout:
//   float xn[NN*DD]      normalized x rows
//   int   cnt[NN]        neighbor count per row (clamped to CAP)
//   int   nbr[NN*CAP]    neighbor indices per row

__global__ __launch_bounds__(256) void build_rows(
    const float* __restrict__ emb, const float* __restrict__ adj,
    float* __restrict__ xn, int* __restrict__ cnt, int* __restrict__ nbr)
{
    const int i = blockIdx.x;
    const int t = threadIdx.x;            // t in [0,256) == dim index
    __shared__ int   s_cnt;
    __shared__ int   s_list[CAP];
    __shared__ float s_red[4];
    __shared__ float s_norm;

    if (t == 0) s_cnt = 0;

    // issue own-row emb load early; it overlaps the adj scan
    const float self = emb[(size_t)i * DD + t];

    __syncthreads();

    // --- scan adjacency row i. Non-temporal loads: adj is read-once (400 MB
    // stream) — keep it from evicting the hot 10 MB emb table out of L2/L3.
    // Preload all 10 float4 back-to-back for max outstanding loads.
    const fx4* row = (const fx4*)(adj + (size_t)i * NN);
    fx4 r[10];
    #pragma unroll
    for (int j = 0; j < 10; ++j) {
        int k = t + j * 256;
        if (k < NN / 4) r[j] = __builtin_nontemporal_load(&row[k]);
        else            r[j] = (fx4){0.f, 0.f, 0.f, 0.f};
    }
    #pragma unroll
    for (int j = 0; j < 10; ++j) {
        fx4 v = r[j];
        int base = (t + j * 256) * 4;
        if (v.x != 0.f) { int p = atomicAdd(&s_cnt, 1); if (p < CAP) s_list[p] = base;     }
        if (v.y != 0.f) { int p = atomicAdd(&s_cnt, 1); if (p < CAP) s_list[p] = base + 1; }
        if (v.z != 0.f) { int p = atomicAdd(&s_cnt, 1); if (p < CAP) s_list[p] = base + 2; }
        if (v.w != 0.f) { int p = atomicAdd(&s_cnt, 1); if (p < CAP) s_list[p] = base + 3; }
    }
    __syncthreads();

    const int c = s_cnt;
    const int m = (c < CAP) ? c : CAP;

    // --- aggregate neighbor embeddings, 8 loads in flight per thread
    float a0=0.f,a1=0.f,a2=0.f,a3=0.f,a4=0.f,a5=0.f,a6=0.f,a7=0.f;
    int k = 0;
    for (; k + 8 <= m; k += 8) {
        int i0=s_list[k],   i1=s_list[k+1], i2=s_list[k+2], i3=s_list[k+3];
        int i4=s_list[k+4], i5=s_list[k+5], i6=s_list[k+6], i7=s_list[k+7];
        a0 += emb[(size_t)i0*DD + t]; a1 += emb[(size_t)i1*DD + t];
        a2 += emb[(size_t)i2*DD + t]; a3 += emb[(size_t)i3*DD + t];
        a4 += emb[(size_t)i4*DD + t]; a5 += emb[(size_t)i5*DD + t];
        a6 += emb[(size_t)i6*DD + t]; a7 += emb[(size_t)i7*DD + t];
    }
    for (; k < m; ++k) a0 += emb[(size_t)s_list[k]*DD + t];
    const float acc = ((a0+a1)+(a2+a3)) + ((a4+a5)+(a6+a7));

    const float deg = (float)c + 1e-6f;
    const float x = self + acc / deg;

    // row norm over 256 threads (4 waves of 64)
    float s = x * x;
    #pragma unroll
    for (int o = 32; o > 0; o >>= 1) s += __shfl_down(s, o, 64);
    const int lane = t & 63, wv = t >> 6;
    if (lane == 0) s_red[wv] = s;
    __syncthreads();
    if (t == 0) {
        float tot = s_red[0] + s_red[1] + s_red[2] + s_red[3];
        s_norm = fmaxf(sqrtf(tot), 1e-8f);
    }
    __syncthreads();

    xn[(size_t)i * DD + t] = x / s_norm;

    if (t == 0) cnt[i] = m;
    for (int q = t; q < m; q += 256) nbr[(size_t)i * CAP + q] = s_list[q];
}

// One wave per edge. Load both FULL CAP-sized nbr rows unconditionally and
// immediately (no dependence on cnt) to collapse the dependent-load chain;
// bound the intersection by cnt afterwards. ~91% of edges have zero common
// neighbors -> sigmoid(0)=0.5 early exit without touching xn.
__global__ __launch_bounds__(64) void edge_weights(
    const int* __restrict__ edges, const float* __restrict__ xn,
    const int* __restrict__ cnt, const int* __restrict__ nbr,
    float* __restrict__ out)
{
    const int e = blockIdx.x;
    const int lane = threadIdx.x;
    const int srcI = edges[e];
    const int dstI = edges[QQ + e];

    __shared__ int s_dst[CAP];
    __shared__ int s_com[CAP];
    __shared__ int s_ncom;

    // all four memory streams issued back-to-back:
    const int2 sA = ((const int2*)(nbr + (size_t)srcI * CAP))[lane];  // src row, 2 entries/lane
    const int2 dA = ((const int2*)(nbr + (size_t)dstI * CAP))[lane];  // dst row
    const int cs = cnt[srcI];
    const int cd = cnt[dstI];

    if (lane == 0) s_ncom = 0;
    s_dst[2 * lane]     = dA.x;
    s_dst[2 * lane + 1] = dA.y;
    __syncthreads();

    // lane owns src entries 2*lane, 2*lane+1
    {
        int k0 = 2 * lane, k1 = 2 * lane + 1;
        if (k0 < cs) {
            bool f = false;
            for (int j = 0; j < cd; ++j) { if (s_dst[j] == sA.x) { f = true; break; } }
            if (f) { int p = atomicAdd(&s_ncom, 1); s_com[p] = sA.x; }
        }
        if (k1 < cs) {
            bool f = false;
            for (int j = 0; j < cd; ++j) { if (s_dst[j] == sA.y) { f = true; break; } }
            if (f) { int p = atomicAdd(&s_ncom, 1); s_com[p] = sA.y; }
        }
    }
    __syncthreads();

    const int nc = s_ncom;
    if (nc == 0) { if (lane == 0) out[e] = 0.5f; return; }

    const float4 vs = ((const float4*)(xn + (size_t)srcI * DD))[lane];
    const float4 vd = ((const float4*)(xn + (size_t)dstI * DD))[lane];

    float w = 0.f;
    for (int q = 0; q < nc; ++q) {
        const float4 vc = ((const float4*)(xn + (size_t)s_com[q] * DD))[lane];
        float a = vs.x*vc.x + vs.y*vc.y + vs.z*vc.z + vs.w*vc.w;
        float b = vd.x*vc.x + vd.y*vc.y + vd.z*vc.z + vd.w*vc.w;
        #pragma unroll
        for (int o = 32; o > 0; o >>= 1) {
            a += __shfl_xor(a, o, 64);
            b += __shfl_xor(b, o, 64);
        }
        w += a * b;
    }
    if (lane == 0) out[e] = 1.f / (1.f + expf(-w));
}

extern "C" void kernel_launch(void* const* d_in, const int* in_sizes, int n_in,
                              void* d_out, int out_size, void* d_ws, size_t ws_size,
                              hipStream_t stream) {
    const float* emb   = (const float*)d_in[0];   // [N, D] fp32
    const float* adj   = (const float*)d_in[1];   // [N, N] fp32 (0/1)
    const int*   edges = (const int*)d_in[2];     // [2, Q] int32
    float*       out   = (float*)d_out;           // [Q] fp32

    float* xn  = (float*)d_ws;
    int*   cnt = (int*)(xn + (size_t)NN * DD);
    int*   nbr = cnt + NN;

    build_rows<<<NN, 256, 0, stream>>>(emb, adj, xn, cnt, nbr);
    edge_weights<<<QQ, 64, 0, stream>>>(edges, xn, cnt, nbr, out);
}